// Round 1
// baseline (1113.199 us; speedup 1.0000x reference)
//
#include <hip/hip_runtime.h>
#include <stdint.h>
#include <stddef.h>

// CharPredictorMultirateFFN on MI355X (gfx950).
// Pipeline: gather(+pad) -> conv_w transpose -> lin_w transpose -> conv GEMM (fp16 MFMA)
//           -> linear GEMM + fused softmax.
//
// R7: remove the vmcnt(0) drains from the conv K-loop. R6 measured MfmaUtil 68.3%
// (= 1272 TF, 61% of the 2075 TF 16x16x32 ceiling) with 64 full drain+barrier pairs
// per block. Replace with a depth-1 counted-vmcnt pipeline (T3+T4): B double-buffered
// in 2-tap phases (32 KB), A slab double-buffered and shrunk 192->144 rows (18 KB,
// only 143 rows are ever read; 16-row tail staged redundantly by all 4 waves to keep
// per-wave vmcnt uniform). Raw s_barrier + s_waitcnt vmcnt(4/7) so next-phase loads
// stay in flight across barriers; setprio(1) around the MFMA cluster (T5). LDS 50 KB
// -> still 3 blocks/CU. Everything else R5/R6-verified: A-slab-per-eblock, XOR
// swizzle (0 conflicts), XCD-pinned grid swizzle, coalesced k_twc.

typedef _Float16 f16;
typedef __attribute__((ext_vector_type(8))) _Float16 f16x8;
typedef __attribute__((ext_vector_type(4))) float f32x4;

#define SP 2063  // padded rows per batch item: 15 + 2048

__device__ __forceinline__ void gl2lds16(const void* g, void* l) {
  __builtin_amdgcn_global_load_lds((const __attribute__((address_space(1))) void*)g,
                                   (__attribute__((address_space(3))) void*)l, 16, 0, 0);
}

// ---------------- gather: emb_table[seq] -> f16 padded buffer [32][2063][512] --------
__global__ __launch_bounds__(256) void k_gather(const int* __restrict__ seq,
                                                const float* __restrict__ tab,
                                                f16* __restrict__ embp) {
  int row = blockIdx.x * 4 + (threadIdx.x >> 6);   // 0 .. 66015
  int lane = threadIdx.x & 63;
  int b = row / SP;
  int r = row - b * SP;
  f16* dst = embp + (size_t)row * 512 + lane * 8;
  if (r < 15) {
    f16x8 z = {(f16)0, (f16)0, (f16)0, (f16)0, (f16)0, (f16)0, (f16)0, (f16)0};
    *(f16x8*)dst = z;
  } else {
    int idx = seq[b * 2048 + (r - 15)];
    const float4* src = (const float4*)(tab + (size_t)idx * 512 + lane * 8);
    float4 v0 = src[0], v1 = src[1];
    f16x8 o;
    o[0] = (f16)v0.x; o[1] = (f16)v0.y; o[2] = (f16)v0.z; o[3] = (f16)v0.w;
    o[4] = (f16)v1.x; o[5] = (f16)v1.y; o[6] = (f16)v1.z; o[7] = (f16)v1.w;
    *(f16x8*)dst = o;
  }
}

// ---------------- conv_w [H][E][K] f32 -> wt2 [256 jk][1024 h][32 e5] f16 ------------
// jk = j*16 + k ; e = j*32 + e5. Coalesced read of one h-row into LDS, transpose out.
__global__ __launch_bounds__(256) void k_twc(const float* __restrict__ cw,
                                             f16* __restrict__ wt2) {
  __shared__ f16 tile[8192];          // [e][k] in source order (16 KB)
  int h = blockIdx.x;                 // 1024 blocks
  const float4* src = (const float4*)(cw + (size_t)h * 8192);
#pragma unroll
  for (int i = 0; i < 8; ++i) {
    int o = i * 256 + threadIdx.x;    // float4 index, fully coalesced
    float4 v = src[o];
    f16* d = tile + o * 4;
    d[0] = (f16)v.x; d[1] = (f16)v.y; d[2] = (f16)v.z; d[3] = (f16)v.w;
  }
  __syncthreads();
  // thread t = j*16+k writes 32 halves: wt2[(t*1024 + h)*32 + e5] = tile[(j*32+e5)*16 + k]
  int j = threadIdx.x >> 4, k = threadIdx.x & 15;
  f16* dst = wt2 + ((size_t)threadIdx.x * 1024 + h) * 32;
#pragma unroll
  for (int c8 = 0; c8 < 4; ++c8) {
    f16x8 v;
#pragma unroll
    for (int t = 0; t < 8; ++t) v[t] = tile[((j * 32 + c8 * 8 + t) << 4) | k];
    *(f16x8*)(dst + c8 * 8) = v;
  }
}

// ---------------- lin_w [V][F] f32 -> lt2 [48 fblk][256 v][32] f16 -------------------
__global__ __launch_bounds__(256) void k_twl(const float* __restrict__ lw,
                                             f16* __restrict__ lt2) {
  int o = blockIdx.x * 256 + threadIdx.x;  // 393216 outputs
  int f5 = o & 31;
  int v = (o >> 5) & 255;
  int kb = o >> 13;            // 0..47
  int f = (kb << 5) | f5;
  lt2[o] = (f16)lw[(size_t)v * 1536 + f];
}

// ---------------- conv GEMM: [65536 x 8192] x [8192 x 1024] -> relu -> f16 -----------
// 128x128 block, 4 waves (2x2 of 64x64 wave tiles, each 4x4 of 16x16 MFMA tiles).
// 128 phases of 2 taps each; depth-1 counted-vmcnt pipeline over dbuf A slab + dbuf B.
__global__ __launch_bounds__(256) void k_conv(const f16* __restrict__ embp,
                                              const f16* __restrict__ wt2,
                                              const float* __restrict__ cb,
                                              f16* __restrict__ cout) {
  __shared__ __align__(16) f16 Asl[2 * 144 * 32];     // 18 KB: A slab dbuf (144 rows)
  __shared__ __align__(16) f16 Bsl[2 * 2 * 128 * 32]; // 32 KB: B dbuf, 2 tap-tiles/phase
  // XCD-pinned swizzle (R3/R5-verified): bid&7 -> XCD, n fastest within.
  int bid = blockIdx.x;
  int x8 = bid & 7;
  int s = bid >> 3;
  int nb = s & 7;
  int mb = ((s >> 3) << 3) | x8;
  int n0 = nb << 7, m0 = mb << 7;
  int b = m0 >> 11, t0 = m0 & 2047;
  int tid = threadIdx.x, lane = tid & 63, wave = tid >> 6;
  int wr = wave >> 1, wc = wave & 1;
  int fr = lane & 15, q = lane >> 4;
  int prl = lane >> 2, pc = lane & 3;   // staging: row-within-64-group, phys chunk

  // A stage sources. c=0,1: rows c*64 + wave*16 + prl (full 128 rows).
  // c=2: rows 128 + (lane>>2), ALL 4 waves redundantly (same data; keeps vmcnt
  // uniform at 3/wave). Source fetches logical chunk pc ^ ((row>>1)&3) (XOR swizzle).
  const f16* gA[3];
#pragma unroll
  for (int c = 0; c < 2; ++c) {
    int pr = c * 64 + wave * 16 + prl;
    int clog = pc ^ ((pr >> 1) & 3);
    gA[c] = embp + (size_t)(b * SP + t0 + pr) * 512 + clog * 8;
  }
  {
    int pr = 128 + prl;                 // prl = lane>>2 in 0..15
    int clog = pc ^ ((pr >> 1) & 3);
    gA[2] = embp + (size_t)(b * SP + t0 + pr) * 512 + clog * 8;
  }
  // B tile staging (2 calls x 4 KB per tile), same swizzle (R2/R5-verified, 0 conflicts).
  const f16* gB[2];
#pragma unroll
  for (int c = 0; c < 2; ++c) {
    int pr = c * 64 + wave * 16 + prl;
    int clog = pc ^ ((pr >> 1) & 3);
    gB[c] = wt2 + (size_t)(n0 + pr) * 32 + clog * 8;
  }

  int fqB = (q ^ ((fr >> 1) & 3)) << 3;         // B frag phys chunk (rows % 16 aligned)

  auto stage_a = [&](int jn) {                  // 3 gl2lds per wave, uniform
    int jc = (jn & 1) * 4608;
#pragma unroll
    for (int c = 0; c < 2; ++c)
      gl2lds16(gA[c] + jn * 32, Asl + jc + c * 2048 + wave * 512);
    gl2lds16(gA[2] + jn * 32, Asl + jc + 4096); // rows 128..143, wave-redundant
  };
  auto stage_b = [&](int pn) {                  // 4 gl2lds per wave
    int cn = (pn & 1) * 8192;
#pragma unroll
    for (int t = 0; t < 2; ++t)
#pragma unroll
      for (int c = 0; c < 2; ++c)
        gl2lds16(gB[c] + (size_t)(2 * pn + t) * 32768,
                 Bsl + cn + t * 4096 + c * 2048 + wave * 512);
  };

  f32x4 zero = {0.f, 0.f, 0.f, 0.f};
  f32x4 acc[4][4];
#pragma unroll
  for (int i = 0; i < 4; ++i)
#pragma unroll
    for (int jj = 0; jj < 4; ++jj) acc[i][jj] = zero;

  // prologue: A(0), B(0)
  stage_a(0);
  stage_b(0);

  // 128 phases: p -> (j = p>>3, taps {2*(p&7), 2*(p&7)+1})
#pragma unroll 1
  for (int p = 0; p < 128; ++p) {
    // barrier #1: all waves done with compute(p-1) -> safe to overwrite buf[(p+1)&1]
    __builtin_amdgcn_s_barrier();
    __builtin_amdgcn_sched_barrier(0);
    if (p < 127) {
      stage_b(p + 1);
      if ((p & 7) == 7) stage_a((p >> 3) + 1);  // A(j+1), consumed from phase p+1
    }
    // counted wait: leave exactly stage(p+1) in flight; stage(p) is then landed.
    if (p == 127)          asm volatile("s_waitcnt vmcnt(0)" ::: "memory");
    else if ((p & 7) == 7) asm volatile("s_waitcnt vmcnt(7)" ::: "memory");
    else                   asm volatile("s_waitcnt vmcnt(4)" ::: "memory");
    // barrier #2: every wave's stage(p) portion is in LDS
    __builtin_amdgcn_s_barrier();
    __builtin_amdgcn_sched_barrier(0);

    const f16* Ac = Asl + ((p >> 3) & 1) * 4608;
    const f16* Bc = Bsl + (p & 1) * 8192;
    __builtin_amdgcn_s_setprio(1);
#pragma unroll
    for (int t = 0; t < 2; ++t) {
      int k = ((p & 7) << 1) + t;
      // A frag: slab row = k + wr*64 + i*16 + fr ; swizzle includes tap offset k.
      int aswz = ((k + fr) >> 1) & 3;
      const f16* ap = Ac + (size_t)(k + wr * 64 + fr) * 32 + ((q ^ aswz) << 3);
      f16x8 af[4], bf[4];
#pragma unroll
      for (int i = 0; i < 4; ++i)
        af[i] = *(const f16x8*)(ap + i * 512);
#pragma unroll
      for (int jj = 0; jj < 4; ++jj)
        bf[jj] = *(const f16x8*)(Bc + t * 4096 + (wc * 64 + jj * 16 + fr) * 32 + fqB);
#pragma unroll
      for (int i = 0; i < 4; ++i)
#pragma unroll
        for (int jj = 0; jj < 4; ++jj)
          acc[i][jj] = __builtin_amdgcn_mfma_f32_16x16x32_f16(af[i], bf[jj], acc[i][jj], 0, 0, 0);
    }
    __builtin_amdgcn_s_setprio(0);
  }

  // epilogue: bias + relu + f16 store. C/D: col=lane&15 (n), row=(lane>>4)*4+reg (m)
  int col = lane & 15, rq = (lane >> 4) << 2;
  int mbase = m0 + wr * 64 + rq;
  int nbase = n0 + wc * 64 + col;
#pragma unroll
  for (int jj = 0; jj < 4; ++jj) {
    int h = nbase + jj * 16;
    float bias = cb[h];
#pragma unroll
    for (int i = 0; i < 4; ++i) {
      int m = mbase + i * 16;
#pragma unroll
      for (int rg = 0; rg < 4; ++rg) {
        float v = acc[i][jj][rg] + bias;
        v = v > 0.f ? v : 0.f;
        cout[(size_t)(m + rg) * 1024 + h] = (f16)v;
      }
    }
  }
}

// ---------------- linear GEMM [65536 x 1536] x [1536 x 256] + fused softmax ----------
__global__ __launch_bounds__(256) void k_lin(const f16* __restrict__ embp,
                                             const f16* __restrict__ cout,
                                             const f16* __restrict__ lt2,
                                             const float* __restrict__ lb,
                                             float* __restrict__ out) {
  __shared__ __align__(16) char smem[32 * 261 * 4];  // Ls overlays As|Bs
  __shared__ float pmax[4][32], psum[4][32], mrow[32], rinv[32];
  f16* As = (f16*)smem;             // [64][32]   4 KB
  f16* Bs = (f16*)(smem + 4096);    // [256][32] 16 KB
  float* Ls = (float*)smem;         // [32][261] f32 epilogue logits
  int m0 = blockIdx.x << 6;
  int b = m0 >> 11, t0 = m0 & 2047;
  int tid = threadIdx.x, lane = tid & 63, wave = tid >> 6;
  int sr = lane >> 2, sc = (lane & 3) << 3;
  const f16* gAe = embp + (size_t)(b * SP + 15 + t0 + wave * 16 + sr) * 512 + sc;
  const f16* gAc = cout + (size_t)(m0 + wave * 16 + sr) * 1024 + sc;
  f16* lA = As + wave * 512;
  int fr = lane & 15, fq = (lane >> 4) << 3;
  f32x4 zero = {0.f, 0.f, 0.f, 0.f};
  f32x4 acc[4][4];
#pragma unroll
  for (int i = 0; i < 4; ++i)
#pragma unroll
    for (int j = 0; j < 4; ++j) acc[i][j] = zero;

  for (int kb = 0; kb < 48; ++kb) {
    if (kb < 16) gl2lds16(gAe + kb * 32, lA);
    else         gl2lds16(gAc + (kb - 16) * 32, lA);
#pragma unroll
    for (int jj = 0; jj < 4; ++jj) {
      int c = wave * 4 + jj;
      gl2lds16(lt2 + (size_t)kb * 8192 + (c * 16 + sr) * 32 + sc, Bs + c * 512);
    }
    __syncthreads();
    f16x8 af[4], bf[4];
#pragma unroll
    for (int i = 0; i < 4; ++i)
      af[i] = *(const f16x8*)(As + (i * 16 + fr) * 32 + fq);
#pragma unroll
    for (int j = 0; j < 4; ++j)
      bf[j] = *(const f16x8*)(Bs + (wave * 64 + j * 16 + fr) * 32 + fq);
#pragma unroll
    for (int i = 0; i < 4; ++i)
#pragma unroll
      for (int j = 0; j < 4; ++j)
        acc[i][j] = __builtin_amdgcn_mfma_f32_16x16x32_f16(af[i], bf[j], acc[i][j], 0, 0, 0);
    __syncthreads();
  }

  // softmax epilogue, two 32-row halves. Ls stride 261 (coprime with 32).
  int col = lane & 15, rq = (lane >> 4) << 2;
  for (int hf = 0; hf < 2; ++hf) {
    __syncthreads();
#pragma unroll
    for (int j = 0; j < 4; ++j) {
      int v = wave * 64 + j * 16 + col;
      float bias = lb[v];
#pragma unroll
      for (int i = 0; i < 2; ++i) {
        int rloc = i * 16 + rq;
        int ig = hf * 2 + i;
#pragma unroll
        for (int rg = 0; rg < 4; ++rg)
          Ls[(rloc + rg) * 261 + v] = acc[ig][j][rg] + bias;
      }
    }
    __syncthreads();
    if (tid < 128) {
      int r = tid & 31, qd = tid >> 5;
      const float* rowp = Ls + r * 261 + qd * 64;
      float pm = -1e30f;
#pragma unroll 8
      for (int c = 0; c < 64; ++c) pm = fmaxf(pm, rowp[c]);
      pmax[qd][r] = pm;
    }
    __syncthreads();
    if (tid < 32)
      mrow[tid] = fmaxf(fmaxf(pmax[0][tid], pmax[1][tid]), fmaxf(pmax[2][tid], pmax[3][tid]));
    __syncthreads();
    if (tid < 128) {
      int r = tid & 31, qd = tid >> 5;
      const float* rowp = Ls + r * 261 + qd * 64;
      float mr = mrow[r], ps = 0.f;
#pragma unroll 8
      for (int c = 0; c < 64; ++c) ps += __expf(rowp[c] - mr);
      psum[qd][r] = ps;
    }
    __syncthreads();
    if (tid < 32)
      rinv[tid] = 1.f / (psum[0][tid] + psum[1][tid] + psum[2][tid] + psum[3][tid]);
    __syncthreads();
    float* obase = out + (size_t)(m0 + hf * 32) * 256 + tid;
#pragma unroll 4
    for (int r = 0; r < 32; ++r)
      obase[(size_t)r * 256] = __expf(Ls[r * 261 + tid] - mrow[r]) * rinv[r];
  }
}

extern "C" void kernel_launch(void* const* d_in, const int* in_sizes, int n_in,
                              void* d_out, int out_size, void* d_ws, size_t ws_size,
                              hipStream_t stream) {
  const int*   seq = (const int*)d_in[0];
  const float* tab = (const float*)d_in[1];
  const float* cw  = (const float*)d_in[2];
  const float* cb  = (const float*)d_in[3];
  const float* lw  = (const float*)d_in[4];
  const float* lb  = (const float*)d_in[5];
  float* out = (float*)d_out;
  char* ws = (char*)d_ws;
  // workspace layout (needs ~219.4 MB):
  f16* embp = (f16*)(ws);               //  67,600,384 B  [32*2063][512]
  f16* cout = (f16*)(ws + 67600384);    // 134,217,728 B  [65536][1024]
  f16* wt2  = (f16*)(ws + 201818112);   //  16,777,216 B  [256 jk][1024 h][32 e5]
  f16* lt2  = (f16*)(ws + 218595328);   //     786,432 B  [48][256][32]

  hipLaunchKernelGGL(k_gather, dim3(16504), dim3(256), 0, stream, seq, tab, embp);
  hipLaunchKernelGGL(k_twc,    dim3(1024),  dim3(256), 0, stream, cw, wt2);
  hipLaunchKernelGGL(k_twl,    dim3(1536),  dim3(256), 0, stream, lw, lt2);
  hipLaunchKernelGGL(k_conv,   dim3(4096),  dim3(256), 0, stream, embp, wt2, cb, cout);
  hipLaunchKernelGGL(k_lin,    dim3(1024),  dim3(256), 0, stream, embp, cout, lt2, lb, out);
}